// Round 6
// baseline (258.378 us; speedup 1.0000x reference)
//
#include <hip/hip_runtime.h>

#define NSAMP 4096
#define NITER 200

// ---------------------------------------------------------------------------
// Setup: inv_item = inv(A^T A + 2*DtD + 5*I) via Woodbury (unchanged from R3:
// circulant Binv via Chebyshev DFT sum, rank-9 correction via parallel GJ).
// ---------------------------------------------------------------------------
__global__ __launch_bounds__(256) void setup_woodbury(const float* __restrict__ A,
                                                      float* __restrict__ inv_out) {
  __shared__ double lamr[64];
  __shared__ float binv[64];
  __shared__ float P[9][64];
  __shared__ float Q[9][64];
  __shared__ double W[9][18];
  const int tid = threadIdx.x;
  const double TWO_PI = 6.283185307179586476925286766559;

  double cb = 0.0;
  if (tid < 64) {
    cb = cos(TWO_PI * (double)tid / 64.0);
    lamr[tid] = 1.0 / (9.0 - 4.0 * cb);
  }
  __syncthreads();
  if (tid < 64) {
    double cm1 = 1.0, c0 = cb;
    double acc = lamr[0] + cb * lamr[1];
#pragma unroll 16
    for (int m = 2; m < 64; ++m) {
      double c = 2.0 * cb * c0 - cm1;
      cm1 = c0;
      c0 = c;
      acc += c * lamr[m];
    }
    binv[tid] = (float)(acc / 64.0);
  }
  __syncthreads();

  for (int e = tid; e < 9 * 64; e += 256) {
    int m = e >> 6, i = e & 63;
    double acc = 0.0;
#pragma unroll 16
    for (int k = 0; k < 64; ++k)
      acc += (double)A[m * 64 + k] * (double)binv[(k - i) & 63];
    P[m][i] = (float)acc;
  }
  __syncthreads();

  if (tid < 81) {
    int m = tid / 9, n = tid % 9;
    double acc = (m == n) ? 1.0 : 0.0;
#pragma unroll 16
    for (int i = 0; i < 64; ++i)
      acc += (double)P[m][i] * (double)A[n * 64 + i];
    W[m][n] = acc;
    W[m][n + 9] = (m == n) ? 1.0 : 0.0;
  }
  __syncthreads();

  {
    const int r9 = tid / 18, c9 = tid % 18;
    const bool act = (tid < 162);
    for (int k = 0; k < 9; ++k) {
      double pv = 1.0, f = 0.0, wkc = 0.0;
      if (act) {
        pv = W[k][k];
        f = W[r9][k];
        wkc = W[k][c9];
      }
      __syncthreads();
      if (act) {
        double nk = wkc / pv;
        W[r9][c9] = (r9 == k) ? nk : fma(-f, nk, W[r9][c9]);
      }
      __syncthreads();
    }
  }

  for (int e = tid; e < 9 * 64; e += 256) {
    int m = e >> 6, j = e & 63;
    double acc = 0.0;
#pragma unroll
    for (int n = 0; n < 9; ++n) acc += W[m][n + 9] * (double)P[n][j];
    Q[m][j] = (float)acc;
  }
  __syncthreads();

  for (int e = tid; e < 64 * 64; e += 256) {
    int i = e >> 6, j = e & 63;
    float acc = binv[(i - j) & 63];
#pragma unroll
    for (int m = 0; m < 9; ++m) acc = fmaf(-P[m][i], Q[m][j], acc);
    inv_out[e] = acc;
  }
}

// ---------------------------------------------------------------------------
// Main ADMM kernel, R6: LDS-instruction pressure moved to the SGPR pipe.
// R5 diagnosis: 19 DS-instr/wave/iter x 16 waves/CU x ~6 cyc = the whole
// 1872 cyc/iter wall (LDS instruction throughput, per-CU shared).
// Now: resid components 0-47 broadcast via v_readlane -> SGPR s40-s87 and
// consumed by v_fmac_f32 (SGPR src0); components 48-63 via 4 ds_read_b128 +
// 8 v_pk_fma_f32. DS ops/iter: 19 -> 7 (write + 4 reads + 2 bpermute).
// One wave per block (4096 blocks) for fine-grained dispatch balance.
// M row in v64-v127, state in v32-v63, all hard physical regs.
// ---------------------------------------------------------------------------
__global__ __launch_bounds__(64)
void admm_kernel(const float* __restrict__ target, const float* __restrict__ A,
                 const float* __restrict__ x0, const float* __restrict__ invmat,
                 float* __restrict__ out) {
  __shared__ __align__(16) float rbuf[64];
  const int lane = threadIdx.x & 63;
  const int s = blockIdx.x;

  // --- ATb = (target_s @ A^T) @ A via 9 wave-reductions (one-time) ---
  float t = target[s * 64 + lane];
  float atbv = 0.f;
#pragma unroll
  for (int m = 0; m < 9; ++m) {
    float a = A[m * 64 + lane];
    float p = t * a;
#pragma unroll
    for (int off = 32; off; off >>= 1) p += __shfl_xor(p, off, 64);
    atbv = fmaf(a, p, atbv);
  }

  const float* mrow = invmat + (size_t)lane * 64;
  unsigned int rb_base = (unsigned int)(uintptr_t)(&rbuf[0]);
  unsigned int a_w = rb_base + lane * 4;
  unsigned int a_nxt = ((lane + 1) & 63) * 4;  // ds_bpermute byte index
  float xin = x0[s * 64 + lane];
  float xout;
  int cnt_s;
  const int smask = 0x7fffffff;
  const float sthr = 5e-5f, sc02 = 0.2f, sc5 = 5.0f;

  asm volatile(
      "s_mov_b32 m0, -1\n\t"
      // --- M row: comps 0-47 -> v64-v111 (fmac path), 48-63 -> v112-v127 ---
      "global_load_dwordx4 v[64:67],   %[mp], off\n\t"
      "global_load_dwordx4 v[68:71],   %[mp], off offset:16\n\t"
      "global_load_dwordx4 v[72:75],   %[mp], off offset:32\n\t"
      "global_load_dwordx4 v[76:79],   %[mp], off offset:48\n\t"
      "global_load_dwordx4 v[80:83],   %[mp], off offset:64\n\t"
      "global_load_dwordx4 v[84:87],   %[mp], off offset:80\n\t"
      "global_load_dwordx4 v[88:91],   %[mp], off offset:96\n\t"
      "global_load_dwordx4 v[92:95],   %[mp], off offset:112\n\t"
      "global_load_dwordx4 v[96:99],   %[mp], off offset:128\n\t"
      "global_load_dwordx4 v[100:103], %[mp], off offset:144\n\t"
      "global_load_dwordx4 v[104:107], %[mp], off offset:160\n\t"
      "global_load_dwordx4 v[108:111], %[mp], off offset:176\n\t"
      "global_load_dwordx4 v[112:115], %[mp], off offset:192\n\t"
      "global_load_dwordx4 v[116:119], %[mp], off offset:208\n\t"
      "global_load_dwordx4 v[120:123], %[mp], off offset:224\n\t"
      "global_load_dwordx4 v[124:127], %[mp], off offset:240\n\t"
      // --- init state: v32=x v33=eta v34=tau v35=Dx v36=atb ---
      "v_mov_b32 v32, %[xin]\n\t"
      "v_mov_b32 v36, %[atb]\n\t"
      "v_mov_b32 v33, 0\n\t"
      "v_mov_b32 v34, 0\n\t"
      "ds_bpermute_b32 v45, %[anx], v32\n\t"
      "s_waitcnt lgkmcnt(0)\n\t"
      "v_sub_f32 v35, v45, v32\n\t"
      "s_movk_i32 %[cnt], 200\n\t"
      "s_waitcnt vmcnt(0)\n\t"
      "1:\n\t"
      // u = copysign(max(|0.5*eta+Dx|-thr,0), .) -> v42
      "v_fma_f32 v40, 0.5, v33, v35\n\t"
      "v_and_b32 v41, %[msk], v40\n\t"
      "v_subrev_f32 v41, %[thr], v41\n\t"
      "v_max_f32 v41, 0, v41\n\t"
      "v_bfi_b32 v42, %[msk], v41, v40\n\t"
      // w = max(0.2*tau + x, 0) -> v43
      "v_fma_f32 v43, %[c02], v34, v32\n\t"
      "v_max_f32 v43, 0, v43\n\t"
      // tv = 2u - eta -> v40 ; ts = tv[lane+1] via bpermute -> v45
      "v_fma_f32 v40, 2.0, v42, -v33\n\t"
      "ds_bpermute_b32 v45, %[anx], v40\n\t"
      // c = 5w + atb - tau - tv -> v44 (overlaps bpermute flight)
      "v_fma_f32 v44, %[c5], v43, v36\n\t"
      "v_sub_f32 v44, v44, v34\n\t"
      "v_sub_f32 v44, v44, v40\n\t"
      "s_waitcnt lgkmcnt(0)\n\t"
      "v_add_f32 v44, v44, v45\n\t"
      // stage resid: write own comp; read back comps 48-63 (in-order DS)
      "ds_write_b32 %[aw], v44\n\t"
      "ds_read_b128 v[48:51], %[rb] offset:192\n\t"
      "ds_read_b128 v[52:55], %[rb] offset:208\n\t"
      "ds_read_b128 v[56:59], %[rb] offset:224\n\t"
      "ds_read_b128 v[60:63], %[rb] offset:240\n\t"
      // V->S broadcast of comps 0-47 (48 readlanes), DS reads fly meanwhile
      "v_readlane_b32 s40, v44, 0\n\t"
      "v_readlane_b32 s41, v44, 1\n\t"
      "v_readlane_b32 s42, v44, 2\n\t"
      "v_readlane_b32 s43, v44, 3\n\t"
      "v_readlane_b32 s44, v44, 4\n\t"
      "v_readlane_b32 s45, v44, 5\n\t"
      "v_readlane_b32 s46, v44, 6\n\t"
      "v_readlane_b32 s47, v44, 7\n\t"
      "v_readlane_b32 s48, v44, 8\n\t"
      "v_readlane_b32 s49, v44, 9\n\t"
      "v_readlane_b32 s50, v44, 10\n\t"
      "v_readlane_b32 s51, v44, 11\n\t"
      "v_readlane_b32 s52, v44, 12\n\t"
      "v_readlane_b32 s53, v44, 13\n\t"
      "v_readlane_b32 s54, v44, 14\n\t"
      "v_readlane_b32 s55, v44, 15\n\t"
      "v_readlane_b32 s56, v44, 16\n\t"
      "v_readlane_b32 s57, v44, 17\n\t"
      "v_readlane_b32 s58, v44, 18\n\t"
      "v_readlane_b32 s59, v44, 19\n\t"
      "v_readlane_b32 s60, v44, 20\n\t"
      "v_readlane_b32 s61, v44, 21\n\t"
      "v_readlane_b32 s62, v44, 22\n\t"
      "v_readlane_b32 s63, v44, 23\n\t"
      "v_readlane_b32 s64, v44, 24\n\t"
      "v_readlane_b32 s65, v44, 25\n\t"
      "v_readlane_b32 s66, v44, 26\n\t"
      "v_readlane_b32 s67, v44, 27\n\t"
      "v_readlane_b32 s68, v44, 28\n\t"
      "v_readlane_b32 s69, v44, 29\n\t"
      "v_readlane_b32 s70, v44, 30\n\t"
      "v_readlane_b32 s71, v44, 31\n\t"
      "v_readlane_b32 s72, v44, 32\n\t"
      "v_readlane_b32 s73, v44, 33\n\t"
      "v_readlane_b32 s74, v44, 34\n\t"
      "v_readlane_b32 s75, v44, 35\n\t"
      "v_readlane_b32 s76, v44, 36\n\t"
      "v_readlane_b32 s77, v44, 37\n\t"
      "v_readlane_b32 s78, v44, 38\n\t"
      "v_readlane_b32 s79, v44, 39\n\t"
      "v_readlane_b32 s80, v44, 40\n\t"
      "v_readlane_b32 s81, v44, 41\n\t"
      "v_readlane_b32 s82, v44, 42\n\t"
      "v_readlane_b32 s83, v44, 43\n\t"
      "v_readlane_b32 s84, v44, 44\n\t"
      "v_readlane_b32 s85, v44, 45\n\t"
      "v_readlane_b32 s86, v44, 46\n\t"
      "v_readlane_b32 s87, v44, 47\n\t"
      // 48 fmac, 4 chains (v37,v38,v39,v41)
      "v_mul_f32 v37, s40, v64\n\t"
      "v_mul_f32 v38, s41, v65\n\t"
      "v_mul_f32 v39, s42, v66\n\t"
      "v_mul_f32 v41, s43, v67\n\t"
      "v_fmac_f32 v37, s44, v68\n\t"
      "v_fmac_f32 v38, s45, v69\n\t"
      "v_fmac_f32 v39, s46, v70\n\t"
      "v_fmac_f32 v41, s47, v71\n\t"
      "v_fmac_f32 v37, s48, v72\n\t"
      "v_fmac_f32 v38, s49, v73\n\t"
      "v_fmac_f32 v39, s50, v74\n\t"
      "v_fmac_f32 v41, s51, v75\n\t"
      "v_fmac_f32 v37, s52, v76\n\t"
      "v_fmac_f32 v38, s53, v77\n\t"
      "v_fmac_f32 v39, s54, v78\n\t"
      "v_fmac_f32 v41, s55, v79\n\t"
      "v_fmac_f32 v37, s56, v80\n\t"
      "v_fmac_f32 v38, s57, v81\n\t"
      "v_fmac_f32 v39, s58, v82\n\t"
      "v_fmac_f32 v41, s59, v83\n\t"
      "v_fmac_f32 v37, s60, v84\n\t"
      "v_fmac_f32 v38, s61, v85\n\t"
      "v_fmac_f32 v39, s62, v86\n\t"
      "v_fmac_f32 v41, s63, v87\n\t"
      "v_fmac_f32 v37, s64, v88\n\t"
      "v_fmac_f32 v38, s65, v89\n\t"
      "v_fmac_f32 v39, s66, v90\n\t"
      "v_fmac_f32 v41, s67, v91\n\t"
      "v_fmac_f32 v37, s68, v92\n\t"
      "v_fmac_f32 v38, s69, v93\n\t"
      "v_fmac_f32 v39, s70, v94\n\t"
      "v_fmac_f32 v41, s71, v95\n\t"
      "v_fmac_f32 v37, s72, v96\n\t"
      "v_fmac_f32 v38, s73, v97\n\t"
      "v_fmac_f32 v39, s74, v98\n\t"
      "v_fmac_f32 v41, s75, v99\n\t"
      "v_fmac_f32 v37, s76, v100\n\t"
      "v_fmac_f32 v38, s77, v101\n\t"
      "v_fmac_f32 v39, s78, v102\n\t"
      "v_fmac_f32 v41, s79, v103\n\t"
      "v_fmac_f32 v37, s80, v104\n\t"
      "v_fmac_f32 v38, s81, v105\n\t"
      "v_fmac_f32 v39, s82, v106\n\t"
      "v_fmac_f32 v41, s83, v107\n\t"
      "v_fmac_f32 v37, s84, v108\n\t"
      "v_fmac_f32 v38, s85, v109\n\t"
      "v_fmac_f32 v39, s86, v110\n\t"
      "v_fmac_f32 v41, s87, v111\n\t"
      // LDS tail: comps 48-63, one packed chain
      "s_waitcnt lgkmcnt(0)\n\t"
      "v_pk_mul_f32 v[46:47], v[112:113], v[48:49]\n\t"
      "v_pk_fma_f32 v[46:47], v[114:115], v[50:51], v[46:47]\n\t"
      "v_pk_fma_f32 v[46:47], v[116:117], v[52:53], v[46:47]\n\t"
      "v_pk_fma_f32 v[46:47], v[118:119], v[54:55], v[46:47]\n\t"
      "v_pk_fma_f32 v[46:47], v[120:121], v[56:57], v[46:47]\n\t"
      "v_pk_fma_f32 v[46:47], v[122:123], v[58:59], v[46:47]\n\t"
      "v_pk_fma_f32 v[46:47], v[124:125], v[60:61], v[46:47]\n\t"
      "v_pk_fma_f32 v[46:47], v[126:127], v[62:63], v[46:47]\n\t"
      // xn = v37+v38+v39+v41+v46+v47 -> v32
      "v_add_f32 v37, v37, v38\n\t"
      "v_add_f32 v39, v39, v41\n\t"
      "v_add_f32 v46, v46, v47\n\t"
      "v_add_f32 v37, v37, v39\n\t"
      "v_add_f32 v32, v37, v46\n\t"
      // Dx = xn[lane+1] - xn ; duals
      "ds_bpermute_b32 v45, %[anx], v32\n\t"
      "s_waitcnt lgkmcnt(0)\n\t"
      "v_sub_f32 v35, v45, v32\n\t"
      "v_sub_f32 v41, v35, v42\n\t"
      "v_fma_f32 v33, 2.0, v41, v33\n\t"
      "v_sub_f32 v41, v32, v43\n\t"
      "v_fma_f32 v34, %[c5], v41, v34\n\t"
      "s_sub_u32 %[cnt], %[cnt], 1\n\t"
      "s_cmp_lg_u32 %[cnt], 0\n\t"
      "s_cbranch_scc1 1b\n\t"
      "v_mov_b32 %[xout], v32\n\t"
      : [xout] "=v"(xout), [cnt] "=&s"(cnt_s)
      : [mp] "v"(mrow), [rb] "v"(rb_base), [aw] "v"(a_w), [anx] "v"(a_nxt),
        [xin] "v"(xin), [atb] "v"(atbv),
        [msk] "s"(smask), [thr] "s"(sthr), [c02] "s"(sc02), [c5] "s"(sc5)
      : "memory", "scc",
        "s40","s41","s42","s43","s44","s45","s46","s47","s48","s49","s50",
        "s51","s52","s53","s54","s55","s56","s57","s58","s59","s60","s61",
        "s62","s63","s64","s65","s66","s67","s68","s69","s70","s71","s72",
        "s73","s74","s75","s76","s77","s78","s79","s80","s81","s82","s83",
        "s84","s85","s86","s87",
        "v32","v33","v34","v35","v36","v37","v38","v39","v40","v41","v42","v43",
        "v44","v45","v46","v47","v48","v49","v50","v51","v52","v53","v54","v55",
        "v56","v57","v58","v59","v60","v61","v62","v63","v64","v65","v66","v67",
        "v68","v69","v70","v71","v72","v73","v74","v75","v76","v77","v78","v79",
        "v80","v81","v82","v83","v84","v85","v86","v87","v88","v89","v90","v91",
        "v92","v93","v94","v95","v96","v97","v98","v99","v100","v101","v102",
        "v103","v104","v105","v106","v107","v108","v109","v110","v111","v112",
        "v113","v114","v115","v116","v117","v118","v119","v120","v121","v122",
        "v123","v124","v125","v126","v127");

  out[s * 64 + lane] = xout;
}

extern "C" void kernel_launch(void* const* d_in, const int* in_sizes, int n_in,
                              void* d_out, int out_size, void* d_ws, size_t ws_size,
                              hipStream_t stream) {
  const float* target = (const float*)d_in[0];  // (4096, 64)
  const float* A = (const float*)d_in[1];       // (9, 64)
  const float* x0 = (const float*)d_in[2];      // (4096, 64)
  float* out = (float*)d_out;                   // (4096, 64)
  float* inv_ws = (float*)d_ws;                 // 64*64 floats scratch

  setup_woodbury<<<1, 256, 0, stream>>>(A, inv_ws);
  admm_kernel<<<NSAMP, 64, 0, stream>>>(target, A, x0, inv_ws, out);
}

// Round 7
// 201.075 us; speedup vs baseline: 1.2850x; 1.2850x over previous
//
#include <hip/hip_runtime.h>

#define NSAMP 4096
#define NITER 200

// ---------------------------------------------------------------------------
// Setup: inv_item = inv(A^T A + 2*DtD + 5*I) via Woodbury (R3 math), but the
// result is written in DPP-PERMUTED order: admm's matvec reads M' such that
// M'[lane][16*s+t] pairs with the value of resid that lane sees at stage s,
// rotation t. The hardware's row_ror direction is PROBED (v_mov_b32_dpp on
// lane ids) so the permutation always matches the silicon.
// ---------------------------------------------------------------------------
__global__ __launch_bounds__(256) void setup_woodbury(const float* __restrict__ A,
                                                      float* __restrict__ mperm) {
  __shared__ double lamr[64];
  __shared__ float binv[64];
  __shared__ float P[9][64];
  __shared__ float Q[9][64];
  __shared__ double W[9][18];
  __shared__ float Mfull[64][64];
  const int tid = threadIdx.x;
  const double TWO_PI = 6.283185307179586476925286766559;

  double cb = 0.0;
  if (tid < 64) {
    cb = cos(TWO_PI * (double)tid / 64.0);
    lamr[tid] = 1.0 / (9.0 - 4.0 * cb);
  }
  __syncthreads();
  if (tid < 64) {
    double cm1 = 1.0, c0 = cb;
    double acc = lamr[0] + cb * lamr[1];
#pragma unroll 16
    for (int m = 2; m < 64; ++m) {
      double c = 2.0 * cb * c0 - cm1;
      cm1 = c0;
      c0 = c;
      acc += c * lamr[m];
    }
    binv[tid] = (float)(acc / 64.0);
  }
  __syncthreads();

  for (int e = tid; e < 9 * 64; e += 256) {
    int m = e >> 6, i = e & 63;
    double acc = 0.0;
#pragma unroll 16
    for (int k = 0; k < 64; ++k)
      acc += (double)A[m * 64 + k] * (double)binv[(k - i) & 63];
    P[m][i] = (float)acc;
  }
  __syncthreads();

  if (tid < 81) {
    int m = tid / 9, n = tid % 9;
    double acc = (m == n) ? 1.0 : 0.0;
#pragma unroll 16
    for (int i = 0; i < 64; ++i)
      acc += (double)P[m][i] * (double)A[n * 64 + i];
    W[m][n] = acc;
    W[m][n + 9] = (m == n) ? 1.0 : 0.0;
  }
  __syncthreads();

  {
    const int r9 = tid / 18, c9 = tid % 18;
    const bool act = (tid < 162);
    for (int k = 0; k < 9; ++k) {
      double pv = 1.0, f = 0.0, wkc = 0.0;
      if (act) {
        pv = W[k][k];
        f = W[r9][k];
        wkc = W[k][c9];
      }
      __syncthreads();
      if (act) {
        double nk = wkc / pv;
        W[r9][c9] = (r9 == k) ? nk : fma(-f, nk, W[r9][c9]);
      }
      __syncthreads();
    }
  }

  for (int e = tid; e < 9 * 64; e += 256) {
    int m = e >> 6, j = e & 63;
    double acc = 0.0;
#pragma unroll
    for (int n = 0; n < 9; ++n) acc += W[m][n + 9] * (double)P[n][j];
    Q[m][j] = (float)acc;
  }
  __syncthreads();

  for (int e = tid; e < 64 * 64; e += 256) {
    int i = e >> 6, j = e & 63;
    float acc = binv[(i - j) & 63];
#pragma unroll
    for (int m = 0; m < 9; ++m) acc = fmaf(-P[m][i], Q[m][j], acc);
    Mfull[i][j] = acc;
  }
  __syncthreads();

  // --- probe DPP row_ror direction, then emit permuted M (wave 0 only) ---
  if (tid < 64) {
    const int lid = tid;
    int dpp1;
    asm volatile(
        "s_nop 4\n\t"
        "v_mov_b32_dpp %0, %1 row_ror:1 row_mask:0xf bank_mask:0xf\n\t"
        "s_nop 4"
        : "=v"(dpp1)
        : "v"(lid));
    const int lane0val = __builtin_amdgcn_readfirstlane(dpp1);
    // lane0 received comp (0 + dir*1) & 15
    const int dir = (lane0val == 1) ? 1 : -1;
    // stage-s register holds comp (reglane ^ xs[s]); view t reads reglane
    // (l&48)|((l+dir*t)&15)
    const int xs4[4] = {0, 16, 48, 32};
    for (int s = 0; s < 4; ++s) {
      for (int t = 0; t < 16; ++t) {
        int q = (lid & 48) | (((lid & 15) + dir * t + 16) & 15);
        int j = q ^ xs4[s];
        mperm[lid * 64 + 16 * s + t] = Mfull[lid][j];
      }
    }
  }
}

// DPP fmac/mul helpers: src0 (the resid register) is read through row_ror:t.
#define DPL(op, acc, rr, mm, rot) \
  op " " acc ", " rr ", " mm " row_ror:" #rot " row_mask:0xf bank_mask:0xf\n\t"

// ---------------------------------------------------------------------------
// Main ADMM kernel, R7: NO LDS BUFFER. Broadcast runs on the VALU via DPP:
// 4 stages x 16 v_fmac_f32 whose src0 reads resid through row_ror:t; stage
// crossings via ds_swizzle xor16 / ds_bpermute xor32 (3 DS ops). DS ops/iter:
// 19 (R5) -> 5. M' (permuted to match probed DPP direction) in v64-v127.
// State v32-v49. 1024 blocks x 4 waves = 16 waves/CU (sample-limited max).
// ---------------------------------------------------------------------------
__global__ __launch_bounds__(256)
void admm_kernel(const float* __restrict__ target, const float* __restrict__ A,
                 const float* __restrict__ x0, const float* __restrict__ mperm,
                 float* __restrict__ out) {
  const int tid = threadIdx.x;
  const int wid = tid >> 6;
  const int lane = tid & 63;
  const int s = blockIdx.x * 4 + wid;

  // --- ATb = (target_s @ A^T) @ A via 9 wave-reductions (one-time) ---
  float t = target[s * 64 + lane];
  float atbv = 0.f;
#pragma unroll
  for (int m = 0; m < 9; ++m) {
    float a = A[m * 64 + lane];
    float p = t * a;
#pragma unroll
    for (int off = 32; off; off >>= 1) p += __shfl_xor(p, off, 64);
    atbv = fmaf(a, p, atbv);
  }

  const float* mrow = mperm + (size_t)lane * 64;
  unsigned int a_nxt = ((lane + 1) & 63) * 4;  // bpermute: pull lane+1
  unsigned int a_x32 = (lane ^ 32) * 4;        // bpermute: pull lane^32
  float xin = x0[s * 64 + lane];
  float xout;
  int cnt_s;
  const int smask = 0x7fffffff;
  const float sthr = 5e-5f, sc02 = 0.2f, sc5 = 5.0f;

  asm volatile(
      "s_mov_b32 m0, -1\n\t"
      // --- M' row into v64-v127 (t-major order, matches fmac sequence) ---
      "global_load_dwordx4 v[64:67],   %[mp], off\n\t"
      "global_load_dwordx4 v[68:71],   %[mp], off offset:16\n\t"
      "global_load_dwordx4 v[72:75],   %[mp], off offset:32\n\t"
      "global_load_dwordx4 v[76:79],   %[mp], off offset:48\n\t"
      "global_load_dwordx4 v[80:83],   %[mp], off offset:64\n\t"
      "global_load_dwordx4 v[84:87],   %[mp], off offset:80\n\t"
      "global_load_dwordx4 v[88:91],   %[mp], off offset:96\n\t"
      "global_load_dwordx4 v[92:95],   %[mp], off offset:112\n\t"
      "global_load_dwordx4 v[96:99],   %[mp], off offset:128\n\t"
      "global_load_dwordx4 v[100:103], %[mp], off offset:144\n\t"
      "global_load_dwordx4 v[104:107], %[mp], off offset:160\n\t"
      "global_load_dwordx4 v[108:111], %[mp], off offset:176\n\t"
      "global_load_dwordx4 v[112:115], %[mp], off offset:192\n\t"
      "global_load_dwordx4 v[116:119], %[mp], off offset:208\n\t"
      "global_load_dwordx4 v[120:123], %[mp], off offset:224\n\t"
      "global_load_dwordx4 v[124:127], %[mp], off offset:240\n\t"
      // --- init: v32=x v33=eta v34=tau v35=Dx v36=atb ---
      "v_mov_b32 v32, %[xin]\n\t"
      "v_mov_b32 v36, %[atb]\n\t"
      "v_mov_b32 v33, 0\n\t"
      "v_mov_b32 v34, 0\n\t"
      "ds_bpermute_b32 v45, %[anx], v32\n\t"
      "s_waitcnt lgkmcnt(0)\n\t"
      "v_sub_f32 v35, v45, v32\n\t"
      "s_movk_i32 %[cnt], 200\n\t"
      "s_waitcnt vmcnt(0)\n\t"
      "1:\n\t"
      // u = copysign(max(|0.5*eta+Dx|-thr,0), .) -> v42
      "v_fma_f32 v40, 0.5, v33, v35\n\t"
      "v_and_b32 v41, %[msk], v40\n\t"
      "v_subrev_f32 v41, %[thr], v41\n\t"
      "v_max_f32 v41, 0, v41\n\t"
      "v_bfi_b32 v42, %[msk], v41, v40\n\t"
      // w = max(0.2*tau + x, 0) -> v43
      "v_fma_f32 v43, %[c02], v34, v32\n\t"
      "v_max_f32 v43, 0, v43\n\t"
      // tv = 2u - eta -> v40 ; ts = tv[lane+1] -> v45
      "v_fma_f32 v40, 2.0, v42, -v33\n\t"
      "ds_bpermute_b32 v45, %[anx], v40\n\t"
      // resid = 5w + atb - tau - tv + ts -> v44
      "v_fma_f32 v44, %[c5], v43, v36\n\t"
      "v_sub_f32 v44, v44, v34\n\t"
      "v_sub_f32 v44, v44, v40\n\t"
      "s_waitcnt lgkmcnt(0)\n\t"
      "v_add_f32 v44, v44, v45\n\t"
      // issue stage-1 source early (xor16)
      "ds_swizzle_b32 v47, v44 offset:0x401F\n\t"
      // ---- stage 0: r=v44, m=v64-79 ----
      "v_mul_f32 v37, v44, v64\n\t"
      DPL("v_mul_f32",  "v38", "v44", "v65", 1)
      DPL("v_mul_f32",  "v39", "v44", "v66", 2)
      DPL("v_mul_f32",  "v46", "v44", "v67", 3)
      DPL("v_fmac_f32", "v37", "v44", "v68", 4)
      DPL("v_fmac_f32", "v38", "v44", "v69", 5)
      DPL("v_fmac_f32", "v39", "v44", "v70", 6)
      DPL("v_fmac_f32", "v46", "v44", "v71", 7)
      DPL("v_fmac_f32", "v37", "v44", "v72", 8)
      DPL("v_fmac_f32", "v38", "v44", "v73", 9)
      DPL("v_fmac_f32", "v39", "v44", "v74", 10)
      DPL("v_fmac_f32", "v46", "v44", "v75", 11)
      DPL("v_fmac_f32", "v37", "v44", "v76", 12)
      DPL("v_fmac_f32", "v38", "v44", "v77", 13)
      DPL("v_fmac_f32", "v39", "v44", "v78", 14)
      DPL("v_fmac_f32", "v46", "v44", "v79", 15)
      "s_waitcnt lgkmcnt(0)\n\t"
      // issue stage-2 source (xor32 via bpermute)
      "ds_bpermute_b32 v48, %[a32], v47\n\t"
      "s_nop 1\n\t"
      // ---- stage 1: r=v47, m=v80-95 ----
      "v_fmac_f32 v37, v47, v80\n\t"
      DPL("v_fmac_f32", "v38", "v47", "v81", 1)
      DPL("v_fmac_f32", "v39", "v47", "v82", 2)
      DPL("v_fmac_f32", "v46", "v47", "v83", 3)
      DPL("v_fmac_f32", "v37", "v47", "v84", 4)
      DPL("v_fmac_f32", "v38", "v47", "v85", 5)
      DPL("v_fmac_f32", "v39", "v47", "v86", 6)
      DPL("v_fmac_f32", "v46", "v47", "v87", 7)
      DPL("v_fmac_f32", "v37", "v47", "v88", 8)
      DPL("v_fmac_f32", "v38", "v47", "v89", 9)
      DPL("v_fmac_f32", "v39", "v47", "v90", 10)
      DPL("v_fmac_f32", "v46", "v47", "v91", 11)
      DPL("v_fmac_f32", "v37", "v47", "v92", 12)
      DPL("v_fmac_f32", "v38", "v47", "v93", 13)
      DPL("v_fmac_f32", "v39", "v47", "v94", 14)
      DPL("v_fmac_f32", "v46", "v47", "v95", 15)
      "s_waitcnt lgkmcnt(0)\n\t"
      // issue stage-3 source (xor16)
      "ds_swizzle_b32 v49, v48 offset:0x401F\n\t"
      "s_nop 1\n\t"
      // ---- stage 2: r=v48, m=v96-111 ----
      "v_fmac_f32 v37, v48, v96\n\t"
      DPL("v_fmac_f32", "v38", "v48", "v97", 1)
      DPL("v_fmac_f32", "v39", "v48", "v98", 2)
      DPL("v_fmac_f32", "v46", "v48", "v99", 3)
      DPL("v_fmac_f32", "v37", "v48", "v100", 4)
      DPL("v_fmac_f32", "v38", "v48", "v101", 5)
      DPL("v_fmac_f32", "v39", "v48", "v102", 6)
      DPL("v_fmac_f32", "v46", "v48", "v103", 7)
      DPL("v_fmac_f32", "v37", "v48", "v104", 8)
      DPL("v_fmac_f32", "v38", "v48", "v105", 9)
      DPL("v_fmac_f32", "v39", "v48", "v106", 10)
      DPL("v_fmac_f32", "v46", "v48", "v107", 11)
      DPL("v_fmac_f32", "v37", "v48", "v108", 12)
      DPL("v_fmac_f32", "v38", "v48", "v109", 13)
      DPL("v_fmac_f32", "v39", "v48", "v110", 14)
      DPL("v_fmac_f32", "v46", "v48", "v111", 15)
      "s_waitcnt lgkmcnt(0)\n\t"
      "s_nop 1\n\t"
      // ---- stage 3: r=v49, m=v112-127 ----
      "v_fmac_f32 v37, v49, v112\n\t"
      DPL("v_fmac_f32", "v38", "v49", "v113", 1)
      DPL("v_fmac_f32", "v39", "v49", "v114", 2)
      DPL("v_fmac_f32", "v46", "v49", "v115", 3)
      DPL("v_fmac_f32", "v37", "v49", "v116", 4)
      DPL("v_fmac_f32", "v38", "v49", "v117", 5)
      DPL("v_fmac_f32", "v39", "v49", "v118", 6)
      DPL("v_fmac_f32", "v46", "v49", "v119", 7)
      DPL("v_fmac_f32", "v37", "v49", "v120", 8)
      DPL("v_fmac_f32", "v38", "v49", "v121", 9)
      DPL("v_fmac_f32", "v39", "v49", "v122", 10)
      DPL("v_fmac_f32", "v46", "v49", "v123", 11)
      DPL("v_fmac_f32", "v37", "v49", "v124", 12)
      DPL("v_fmac_f32", "v38", "v49", "v125", 13)
      DPL("v_fmac_f32", "v39", "v49", "v126", 14)
      DPL("v_fmac_f32", "v46", "v49", "v127", 15)
      // combine -> x_new in v32
      "v_add_f32 v37, v37, v38\n\t"
      "v_add_f32 v39, v39, v46\n\t"
      "v_add_f32 v32, v37, v39\n\t"
      // Dx = x[lane+1] - x ; duals
      "ds_bpermute_b32 v45, %[anx], v32\n\t"
      "v_sub_f32 v41, v32, v43\n\t"
      "v_fma_f32 v34, %[c5], v41, v34\n\t"
      "s_waitcnt lgkmcnt(0)\n\t"
      "v_sub_f32 v35, v45, v32\n\t"
      "v_sub_f32 v41, v35, v42\n\t"
      "v_fma_f32 v33, 2.0, v41, v33\n\t"
      "s_sub_u32 %[cnt], %[cnt], 1\n\t"
      "s_cmp_lg_u32 %[cnt], 0\n\t"
      "s_cbranch_scc1 1b\n\t"
      "v_mov_b32 %[xout], v32\n\t"
      : [xout] "=v"(xout), [cnt] "=&s"(cnt_s)
      : [mp] "v"(mrow), [anx] "v"(a_nxt), [a32] "v"(a_x32),
        [xin] "v"(xin), [atb] "v"(atbv),
        [msk] "s"(smask), [thr] "s"(sthr), [c02] "s"(sc02), [c5] "s"(sc5)
      : "memory", "scc",
        "v32","v33","v34","v35","v36","v37","v38","v39","v40","v41","v42","v43",
        "v44","v45","v46","v47","v48","v49","v64","v65","v66","v67",
        "v68","v69","v70","v71","v72","v73","v74","v75","v76","v77","v78","v79",
        "v80","v81","v82","v83","v84","v85","v86","v87","v88","v89","v90","v91",
        "v92","v93","v94","v95","v96","v97","v98","v99","v100","v101","v102",
        "v103","v104","v105","v106","v107","v108","v109","v110","v111","v112",
        "v113","v114","v115","v116","v117","v118","v119","v120","v121","v122",
        "v123","v124","v125","v126","v127");

  out[s * 64 + lane] = xout;
}

extern "C" void kernel_launch(void* const* d_in, const int* in_sizes, int n_in,
                              void* d_out, int out_size, void* d_ws, size_t ws_size,
                              hipStream_t stream) {
  const float* target = (const float*)d_in[0];  // (4096, 64)
  const float* A = (const float*)d_in[1];       // (9, 64)
  const float* x0 = (const float*)d_in[2];      // (4096, 64)
  float* out = (float*)d_out;                   // (4096, 64)
  float* mperm = (float*)d_ws;                  // 64*64 floats (permuted M)

  setup_woodbury<<<1, 256, 0, stream>>>(A, mperm);
  admm_kernel<<<NSAMP / 4, 256, 0, stream>>>(target, A, x0, mperm, out);
}

// Round 8
// 195.855 us; speedup vs baseline: 1.3192x; 1.0267x over previous
//
#include <hip/hip_runtime.h>

#define NSAMP 4096
#define NITER 200

// ---------------------------------------------------------------------------
// Setup: inv_item = inv(A^T A + 2*DtD + 5*I) via Woodbury (R3 math). Output
// written in the order the R8 matvec consumes it:
//   cols  0-47: stages 0-2 (DPP row_ror broadcasts of r, r^16, r^48),
//               permuted per the PROBED hardware rotation direction.
//   cols 48-63: stage 3 (LDS path, r^32 block), quad-STAGGERED per 16-lane
//               group ((g+t)&3) so the 4 concurrent ds_read_b128 addresses
//               hit disjoint LDS banks.
// ---------------------------------------------------------------------------
__global__ __launch_bounds__(256) void setup_woodbury(const float* __restrict__ A,
                                                      float* __restrict__ mperm) {
  __shared__ double lamr[64];
  __shared__ float binv[64];
  __shared__ float P[9][64];
  __shared__ float Q[9][64];
  __shared__ double W[9][18];
  __shared__ float Mfull[64][64];
  const int tid = threadIdx.x;
  const double TWO_PI = 6.283185307179586476925286766559;

  double cb = 0.0;
  if (tid < 64) {
    cb = cos(TWO_PI * (double)tid / 64.0);
    lamr[tid] = 1.0 / (9.0 - 4.0 * cb);
  }
  __syncthreads();
  if (tid < 64) {
    double cm1 = 1.0, c0 = cb;
    double acc = lamr[0] + cb * lamr[1];
#pragma unroll 16
    for (int m = 2; m < 64; ++m) {
      double c = 2.0 * cb * c0 - cm1;
      cm1 = c0;
      c0 = c;
      acc += c * lamr[m];
    }
    binv[tid] = (float)(acc / 64.0);
  }
  __syncthreads();

  for (int e = tid; e < 9 * 64; e += 256) {
    int m = e >> 6, i = e & 63;
    double acc = 0.0;
#pragma unroll 16
    for (int k = 0; k < 64; ++k)
      acc += (double)A[m * 64 + k] * (double)binv[(k - i) & 63];
    P[m][i] = (float)acc;
  }
  __syncthreads();

  if (tid < 81) {
    int m = tid / 9, n = tid % 9;
    double acc = (m == n) ? 1.0 : 0.0;
#pragma unroll 16
    for (int i = 0; i < 64; ++i)
      acc += (double)P[m][i] * (double)A[n * 64 + i];
    W[m][n] = acc;
    W[m][n + 9] = (m == n) ? 1.0 : 0.0;
  }
  __syncthreads();

  {
    const int r9 = tid / 18, c9 = tid % 18;
    const bool act = (tid < 162);
    for (int k = 0; k < 9; ++k) {
      double pv = 1.0, f = 0.0, wkc = 0.0;
      if (act) {
        pv = W[k][k];
        f = W[r9][k];
        wkc = W[k][c9];
      }
      __syncthreads();
      if (act) {
        double nk = wkc / pv;
        W[r9][c9] = (r9 == k) ? nk : fma(-f, nk, W[r9][c9]);
      }
      __syncthreads();
    }
  }

  for (int e = tid; e < 9 * 64; e += 256) {
    int m = e >> 6, j = e & 63;
    double acc = 0.0;
#pragma unroll
    for (int n = 0; n < 9; ++n) acc += W[m][n + 9] * (double)P[n][j];
    Q[m][j] = (float)acc;
  }
  __syncthreads();

  for (int e = tid; e < 64 * 64; e += 256) {
    int i = e >> 6, j = e & 63;
    float acc = binv[(i - j) & 63];
#pragma unroll
    for (int m = 0; m < 9; ++m) acc = fmaf(-P[m][i], Q[m][j], acc);
    Mfull[i][j] = acc;
  }
  __syncthreads();

  // --- probe DPP row_ror direction (per-wave, identical result) ---
  const int lidw = tid & 63;
  int dpp1;
  asm volatile(
      "s_nop 4\n\t"
      "v_mov_b32_dpp %0, %1 row_ror:1 row_mask:0xf bank_mask:0xf\n\t"
      "s_nop 4"
      : "=v"(dpp1)
      : "v"(lidw));
  const int lane0val = __builtin_amdgcn_readfirstlane(dpp1);
  const int dir = (lane0val == 1) ? 1 : -1;

  // --- emit permuted M with all 256 threads ---
  for (int e = tid; e < 64 * 64; e += 256) {
    int li = e >> 6, k = e & 63;
    int j;
    if (k < 48) {
      int st = k >> 4, t = k & 15;
      int xs = (st == 0) ? 0 : (st == 1 ? 16 : 48);
      int q = (li & 48) | (((li & 15) + dir * t + 16) & 15);
      j = q ^ xs;
    } else {
      int t = (k - 48) >> 2, ee = k & 3;
      j = ((li & 48) ^ 32) + 4 * ((((li >> 4) & 3) + t) & 3) + ee;
    }
    mperm[li * 64 + k] = Mfull[li][j];
  }
}

// DPP fmac/mul: src0 (resid register) read through row_ror:t.
#define DPL(op, acc, rr, mm, rot) \
  op " " acc ", " rr ", " mm " row_ror:" #rot " row_mask:0xf bank_mask:0xf\n\t"

// ---------------------------------------------------------------------------
// Main ADMM kernel, R8: dual-pipe matvec.
// R5 = pure LDS = DS-bound (1872 cyc/iter); R7 = pure DPP = VALU-bound at
// DPP ~4cyc (1764). Balance point: 48 elements on DPP (stages 0-2: r, r^16,
// r^48 via 1 ds_swizzle + 1 ds_bpermute), 16 elements (the r^32 block) via
// LDS: 1 ds_write + 4 staggered ds_read_b128 + 8 v_pk_fma_f32 (2cyc/pair).
// Reads are issued before stage 0 and land under 32 DPP fmacs of latency
// cover (counted lgkmcnt, no premature drain). Quad stagger (g+t)&3 makes
// the 4 concurrent read addresses bank-disjoint; M' cols 48-63 permuted to
// match. Model: VALU ~1064, DS ~893 cyc/CU-iter -> ~95-105us.
// ---------------------------------------------------------------------------
__global__ __launch_bounds__(256)
void admm_kernel(const float* __restrict__ target, const float* __restrict__ A,
                 const float* __restrict__ x0, const float* __restrict__ mperm,
                 float* __restrict__ out) {
  __shared__ __align__(16) float rbuf[4][64];
  const int tid = threadIdx.x;
  const int wid = tid >> 6;
  const int lane = tid & 63;
  const int s = blockIdx.x * 4 + wid;

  // --- ATb = (target_s @ A^T) @ A via 9 wave-reductions (one-time) ---
  float t = target[s * 64 + lane];
  float atbv = 0.f;
#pragma unroll
  for (int m = 0; m < 9; ++m) {
    float a = A[m * 64 + lane];
    float p = t * a;
#pragma unroll
    for (int off = 32; off; off >>= 1) p += __shfl_xor(p, off, 64);
    atbv = fmaf(a, p, atbv);
  }

  const float* mrow = mperm + (size_t)lane * 64;
  unsigned int rb_base = (unsigned int)(uintptr_t)(&rbuf[wid][0]);
  unsigned int a_w = rb_base + lane * 4;
  unsigned int a_nxt = ((lane + 1) & 63) * 4;  // bpermute: pull lane+1
  unsigned int a_x32 = (lane ^ 32) * 4;        // bpermute: pull lane^32
  // stage-3 read addresses: base = xor-32 block, quad staggered by group
  unsigned int g = (lane >> 4) & 3;
  unsigned int base3 = rb_base + (((lane & 48) ^ 32) << 2);
  unsigned int aq0 = base3 + (((g + 0) & 3) << 4);
  unsigned int aq1 = base3 + (((g + 1) & 3) << 4);
  unsigned int aq2 = base3 + (((g + 2) & 3) << 4);
  unsigned int aq3 = base3 + (((g + 3) & 3) << 4);
  float xin = x0[s * 64 + lane];
  float xout;
  int cnt_s;
  const int smask = 0x7fffffff;
  const float sthr = 5e-5f, sc02 = 0.2f, sc5 = 5.0f;

  asm volatile(
      "s_mov_b32 m0, -1\n\t"
      // --- M' row into v64-v127 ---
      "global_load_dwordx4 v[64:67],   %[mp], off\n\t"
      "global_load_dwordx4 v[68:71],   %[mp], off offset:16\n\t"
      "global_load_dwordx4 v[72:75],   %[mp], off offset:32\n\t"
      "global_load_dwordx4 v[76:79],   %[mp], off offset:48\n\t"
      "global_load_dwordx4 v[80:83],   %[mp], off offset:64\n\t"
      "global_load_dwordx4 v[84:87],   %[mp], off offset:80\n\t"
      "global_load_dwordx4 v[88:91],   %[mp], off offset:96\n\t"
      "global_load_dwordx4 v[92:95],   %[mp], off offset:112\n\t"
      "global_load_dwordx4 v[96:99],   %[mp], off offset:128\n\t"
      "global_load_dwordx4 v[100:103], %[mp], off offset:144\n\t"
      "global_load_dwordx4 v[104:107], %[mp], off offset:160\n\t"
      "global_load_dwordx4 v[108:111], %[mp], off offset:176\n\t"
      "global_load_dwordx4 v[112:115], %[mp], off offset:192\n\t"
      "global_load_dwordx4 v[116:119], %[mp], off offset:208\n\t"
      "global_load_dwordx4 v[120:123], %[mp], off offset:224\n\t"
      "global_load_dwordx4 v[124:127], %[mp], off offset:240\n\t"
      // --- init: v32=x v33=eta v34=tau v35=Dx v36=atb ---
      "v_mov_b32 v32, %[xin]\n\t"
      "v_mov_b32 v36, %[atb]\n\t"
      "v_mov_b32 v33, 0\n\t"
      "v_mov_b32 v34, 0\n\t"
      "ds_bpermute_b32 v45, %[anx], v32\n\t"
      "s_waitcnt lgkmcnt(0)\n\t"
      "v_sub_f32 v35, v45, v32\n\t"
      "s_movk_i32 %[cnt], 200\n\t"
      "s_waitcnt vmcnt(0)\n\t"
      "1:\n\t"
      // u = copysign(max(|0.5*eta+Dx|-thr,0), .) -> v42
      "v_fma_f32 v40, 0.5, v33, v35\n\t"
      "v_and_b32 v41, %[msk], v40\n\t"
      "v_subrev_f32 v41, %[thr], v41\n\t"
      "v_max_f32 v41, 0, v41\n\t"
      "v_bfi_b32 v42, %[msk], v41, v40\n\t"
      // w = max(0.2*tau + x, 0) -> v43
      "v_fma_f32 v43, %[c02], v34, v32\n\t"
      "v_max_f32 v43, 0, v43\n\t"
      // tv = 2u - eta -> v40 ; ts = tv[lane+1] -> v45
      "v_fma_f32 v40, 2.0, v42, -v33\n\t"
      "ds_bpermute_b32 v45, %[anx], v40\n\t"
      // resid = 5w + atb - tau - tv + ts -> v44
      "v_fma_f32 v44, %[c5], v43, v36\n\t"
      "v_sub_f32 v44, v44, v34\n\t"
      "v_sub_f32 v44, v44, v40\n\t"
      "s_waitcnt lgkmcnt(0)\n\t"
      "v_add_f32 v44, v44, v45\n\t"
      // stage-1 source (xor16), resid store, stage-3 quad reads (staggered)
      "ds_swizzle_b32 v45, v44 offset:0x401F\n\t"
      "ds_write_b32 %[aw], v44\n\t"
      "ds_read_b128 v[48:51], %[aq0]\n\t"
      "ds_read_b128 v[52:55], %[aq1]\n\t"
      "ds_read_b128 v[56:59], %[aq2]\n\t"
      "ds_read_b128 v[60:63], %[aq3]\n\t"
      // ---- stage 0: r=v44, m=v64-79 (reads fly underneath) ----
      "v_mul_f32 v37, v44, v64\n\t"
      DPL("v_mul_f32",  "v38", "v44", "v65", 1)
      DPL("v_mul_f32",  "v39", "v44", "v66", 2)
      DPL("v_mul_f32",  "v40", "v44", "v67", 3)
      DPL("v_fmac_f32", "v37", "v44", "v68", 4)
      DPL("v_fmac_f32", "v38", "v44", "v69", 5)
      DPL("v_fmac_f32", "v39", "v44", "v70", 6)
      DPL("v_fmac_f32", "v40", "v44", "v71", 7)
      DPL("v_fmac_f32", "v37", "v44", "v72", 8)
      DPL("v_fmac_f32", "v38", "v44", "v73", 9)
      DPL("v_fmac_f32", "v39", "v44", "v74", 10)
      DPL("v_fmac_f32", "v40", "v44", "v75", 11)
      DPL("v_fmac_f32", "v37", "v44", "v76", 12)
      DPL("v_fmac_f32", "v38", "v44", "v77", 13)
      DPL("v_fmac_f32", "v39", "v44", "v78", 14)
      DPL("v_fmac_f32", "v40", "v44", "v79", 15)
      // swizzle (oldest of 6 outstanding) done when <=5 remain
      "s_waitcnt lgkmcnt(5)\n\t"
      "ds_bpermute_b32 v46, %[a32], v45\n\t"
      "s_nop 1\n\t"
      // ---- stage 1: r=v45 (xor16), m=v80-95 ----
      "v_fmac_f32 v37, v45, v80\n\t"
      DPL("v_fmac_f32", "v38", "v45", "v81", 1)
      DPL("v_fmac_f32", "v39", "v45", "v82", 2)
      DPL("v_fmac_f32", "v40", "v45", "v83", 3)
      DPL("v_fmac_f32", "v37", "v45", "v84", 4)
      DPL("v_fmac_f32", "v38", "v45", "v85", 5)
      DPL("v_fmac_f32", "v39", "v45", "v86", 6)
      DPL("v_fmac_f32", "v40", "v45", "v87", 7)
      DPL("v_fmac_f32", "v37", "v45", "v88", 8)
      DPL("v_fmac_f32", "v38", "v45", "v89", 9)
      DPL("v_fmac_f32", "v39", "v45", "v90", 10)
      DPL("v_fmac_f32", "v40", "v45", "v91", 11)
      DPL("v_fmac_f32", "v37", "v45", "v92", 12)
      DPL("v_fmac_f32", "v38", "v45", "v93", 13)
      DPL("v_fmac_f32", "v39", "v45", "v94", 14)
      DPL("v_fmac_f32", "v40", "v45", "v95", 15)
      // all DS (write, 4 reads, bpermute) drained; stage-3 data + v46 ready
      "s_waitcnt lgkmcnt(0)\n\t"
      "s_nop 1\n\t"
      // ---- stage 2: r=v46 (xor48), m=v96-111 ----
      "v_fmac_f32 v37, v46, v96\n\t"
      DPL("v_fmac_f32", "v38", "v46", "v97", 1)
      DPL("v_fmac_f32", "v39", "v46", "v98", 2)
      DPL("v_fmac_f32", "v40", "v46", "v99", 3)
      DPL("v_fmac_f32", "v37", "v46", "v100", 4)
      DPL("v_fmac_f32", "v38", "v46", "v101", 5)
      DPL("v_fmac_f32", "v39", "v46", "v102", 6)
      DPL("v_fmac_f32", "v40", "v46", "v103", 7)
      DPL("v_fmac_f32", "v37", "v46", "v104", 8)
      DPL("v_fmac_f32", "v38", "v46", "v105", 9)
      DPL("v_fmac_f32", "v39", "v46", "v106", 10)
      DPL("v_fmac_f32", "v40", "v46", "v107", 11)
      DPL("v_fmac_f32", "v37", "v46", "v108", 12)
      DPL("v_fmac_f32", "v38", "v46", "v109", 13)
      DPL("v_fmac_f32", "v39", "v46", "v110", 14)
      DPL("v_fmac_f32", "v40", "v46", "v111", 15)
      // ---- stage 3: xor-32 block via LDS quads, packed fp32 ----
      "v_pk_mul_f32 v[44:45], v[112:113], v[48:49]\n\t"
      "v_pk_mul_f32 v[46:47], v[114:115], v[50:51]\n\t"
      "v_pk_fma_f32 v[44:45], v[116:117], v[52:53], v[44:45]\n\t"
      "v_pk_fma_f32 v[46:47], v[118:119], v[54:55], v[46:47]\n\t"
      "v_pk_fma_f32 v[44:45], v[120:121], v[56:57], v[44:45]\n\t"
      "v_pk_fma_f32 v[46:47], v[122:123], v[58:59], v[46:47]\n\t"
      "v_pk_fma_f32 v[44:45], v[124:125], v[60:61], v[44:45]\n\t"
      "v_pk_fma_f32 v[46:47], v[126:127], v[62:63], v[46:47]\n\t"
      // combine -> x_new in v32
      "v_add_f32 v37, v37, v38\n\t"
      "v_add_f32 v39, v39, v40\n\t"
      "v_pk_add_f32 v[44:45], v[44:45], v[46:47]\n\t"
      "v_add_f32 v37, v37, v39\n\t"
      "v_add_f32 v44, v44, v45\n\t"
      "v_add_f32 v32, v37, v44\n\t"
      // Dx = x[lane+1] - x ; duals (overlap bpermute latency)
      "ds_bpermute_b32 v45, %[anx], v32\n\t"
      "v_sub_f32 v41, v32, v43\n\t"
      "v_fma_f32 v34, %[c5], v41, v34\n\t"
      "s_waitcnt lgkmcnt(0)\n\t"
      "v_sub_f32 v35, v45, v32\n\t"
      "v_sub_f32 v41, v35, v42\n\t"
      "v_fma_f32 v33, 2.0, v41, v33\n\t"
      "s_sub_u32 %[cnt], %[cnt], 1\n\t"
      "s_cmp_lg_u32 %[cnt], 0\n\t"
      "s_cbranch_scc1 1b\n\t"
      "v_mov_b32 %[xout], v32\n\t"
      : [xout] "=v"(xout), [cnt] "=&s"(cnt_s)
      : [mp] "v"(mrow), [aw] "v"(a_w), [anx] "v"(a_nxt), [a32] "v"(a_x32),
        [aq0] "v"(aq0), [aq1] "v"(aq1), [aq2] "v"(aq2), [aq3] "v"(aq3),
        [xin] "v"(xin), [atb] "v"(atbv),
        [msk] "s"(smask), [thr] "s"(sthr), [c02] "s"(sc02), [c5] "s"(sc5)
      : "memory", "scc",
        "v32","v33","v34","v35","v36","v37","v38","v39","v40","v41","v42","v43",
        "v44","v45","v46","v47","v48","v49","v50","v51","v52","v53","v54","v55",
        "v56","v57","v58","v59","v60","v61","v62","v63","v64","v65","v66","v67",
        "v68","v69","v70","v71","v72","v73","v74","v75","v76","v77","v78","v79",
        "v80","v81","v82","v83","v84","v85","v86","v87","v88","v89","v90","v91",
        "v92","v93","v94","v95","v96","v97","v98","v99","v100","v101","v102",
        "v103","v104","v105","v106","v107","v108","v109","v110","v111","v112",
        "v113","v114","v115","v116","v117","v118","v119","v120","v121","v122",
        "v123","v124","v125","v126","v127");

  out[s * 64 + lane] = xout;
}

extern "C" void kernel_launch(void* const* d_in, const int* in_sizes, int n_in,
                              void* d_out, int out_size, void* d_ws, size_t ws_size,
                              hipStream_t stream) {
  const float* target = (const float*)d_in[0];  // (4096, 64)
  const float* A = (const float*)d_in[1];       // (9, 64)
  const float* x0 = (const float*)d_in[2];      // (4096, 64)
  float* out = (float*)d_out;                   // (4096, 64)
  float* mperm = (float*)d_ws;                  // 64*64 floats (permuted M)

  setup_woodbury<<<1, 256, 0, stream>>>(A, mperm);
  admm_kernel<<<NSAMP / 4, 256, 0, stream>>>(target, A, x0, mperm, out);
}

// Round 9
// 187.423 us; speedup vs baseline: 1.3786x; 1.0450x over previous
//
#include <hip/hip_runtime.h>

#define NSAMP 4096
#define NITER 200

// DPP fmac/mul: src0 (resid register) read through row_ror:t.
#define DPL(op, acc, rr, mm, rot) \
  op " " acc ", " rr ", " mm " row_ror:" #rot " row_mask:0xf bank_mask:0xf\n\t"

// ---------------------------------------------------------------------------
// R9: ONE fused kernel. Each block redundantly computes the Woodbury inverse
// (inv(A^T A + 2 DtD + 5 I) via circulant Binv + rank-9 correction) into its
// own LDS (~3us at full clock, in parallel across all blocks) — this deletes
// the separate 1-block setup kernel whose launch+low-clock cost was ~49us of
// the R5-R8 total.
// Matvec rebalanced d=48->32 (measured: DPP-fmac=4cyc, plain fmac=2cyc,
// pk_fma=4cyc i.e. fp32 rate is fixed; DS-op ~6.2cyc CU-shared):
//   cols  0-31: stages 0-1, DPP row_ror broadcasts of r and r^16 (1 swizzle)
//   cols 32-63: far 32-half [(lane&32)^32 .. +32) via 8 ds_read_b128
//               (2-address broadcast, conflict-free) + 32 plain v_fmac_f32.
// DS/iter = 2 bperm + 1 swizzle + 1 write + 8 reads = 12.
// LDS pool hand-packed to 39952B -> 4 blocks/CU preserved.
// ---------------------------------------------------------------------------
__global__ __launch_bounds__(256)
void admm_fused(const float* __restrict__ target, const float* __restrict__ A,
                const float* __restrict__ x0, float* __restrict__ out) {
  __shared__ __align__(16) char smem[39952];
  float (*Mfull)[64] = (float(*)[64])(smem);          // 16384
  float* Mperm       = (float*)(smem + 16384);        // 16384
  float (*rbuf)[64]  = (float(*)[64])(smem + 32768);  // 1024 (aliases lamr)
  double* lamr       = (double*)(smem + 32768);       // 512, dead before rbuf
  float* binv        = (float*)(smem + 33792);        // 256
  float (*P)[64]     = (float(*)[64])(smem + 34048);  // 2304
  float (*Q)[64]     = (float(*)[64])(smem + 36352);  // 2304
  double (*W)[18]    = (double(*)[18])(smem + 38656); // 1296

  const int tid = threadIdx.x;
  const int wid = tid >> 6;
  const int lane = tid & 63;
  const int s = blockIdx.x * 4 + wid;
  const double TWO_PI = 6.283185307179586476925286766559;

  // ---- setup phase (per block, ~3us) ----
  double cb = 0.0;
  if (tid < 64) {
    cb = cos(TWO_PI * (double)tid / 64.0);
    lamr[tid] = 1.0 / (9.0 - 4.0 * cb);
  }
  __syncthreads();
  if (tid < 64) {
    double cm1 = 1.0, c0 = cb;
    double acc = lamr[0] + cb * lamr[1];
#pragma unroll 16
    for (int m = 2; m < 64; ++m) {
      double c = 2.0 * cb * c0 - cm1;
      cm1 = c0;
      c0 = c;
      acc += c * lamr[m];
    }
    binv[tid] = (float)(acc / 64.0);
  }
  __syncthreads();

  for (int e = tid; e < 9 * 64; e += 256) {
    int m = e >> 6, i = e & 63;
    double acc = 0.0;
#pragma unroll 16
    for (int k = 0; k < 64; ++k)
      acc += (double)A[m * 64 + k] * (double)binv[(k - i) & 63];
    P[m][i] = (float)acc;
  }
  __syncthreads();

  if (tid < 81) {
    int m = tid / 9, n = tid % 9;
    double acc = (m == n) ? 1.0 : 0.0;
#pragma unroll 16
    for (int i = 0; i < 64; ++i)
      acc += (double)P[m][i] * (double)A[n * 64 + i];
    W[m][n] = acc;
    W[m][n + 9] = (m == n) ? 1.0 : 0.0;
  }
  __syncthreads();

  {
    const int r9 = tid / 18, c9 = tid % 18;
    const bool act = (tid < 162);
    for (int k = 0; k < 9; ++k) {
      double pv = 1.0, f = 0.0, wkc = 0.0;
      if (act) {
        pv = W[k][k];
        f = W[r9][k];
        wkc = W[k][c9];
      }
      __syncthreads();
      if (act) {
        double nk = wkc / pv;
        W[r9][c9] = (r9 == k) ? nk : fma(-f, nk, W[r9][c9]);
      }
      __syncthreads();
    }
  }

  for (int e = tid; e < 9 * 64; e += 256) {
    int m = e >> 6, j = e & 63;
    double acc = 0.0;
#pragma unroll
    for (int n = 0; n < 9; ++n) acc += W[m][n + 9] * (double)P[n][j];
    Q[m][j] = (float)acc;
  }
  __syncthreads();

  for (int e = tid; e < 64 * 64; e += 256) {
    int i = e >> 6, j = e & 63;
    float acc = binv[(i - j) & 63];
#pragma unroll
    for (int m = 0; m < 9; ++m) acc = fmaf(-P[m][i], Q[m][j], acc);
    Mfull[i][j] = acc;
  }
  __syncthreads();

  // probe DPP row_ror direction (register-only, per wave)
  int dpp1;
  asm volatile(
      "s_nop 4\n\t"
      "v_mov_b32_dpp %0, %1 row_ror:1 row_mask:0xf bank_mask:0xf\n\t"
      "s_nop 4"
      : "=v"(dpp1)
      : "v"(lane));
  const int dir = (__builtin_amdgcn_readfirstlane(dpp1) == 1) ? 1 : -1;

  // emit permuted M into LDS
  for (int e = tid; e < 64 * 64; e += 256) {
    int li = e >> 6, k = e & 63;
    int j;
    if (k < 32) {
      int t = k & 15;
      int q = (li & 48) | (((li & 15) + dir * t + 16) & 15);
      j = (k < 16) ? q : (q ^ 16);
    } else {
      j = ((li & 32) ^ 32) + (k - 32);
    }
    Mperm[li * 64 + k] = Mfull[li][j];
  }
  __syncthreads();

  // ---- ATb = (target_s @ A^T) @ A via 9 wave-reductions ----
  float t = target[s * 64 + lane];
  float atbv = 0.f;
#pragma unroll
  for (int m = 0; m < 9; ++m) {
    float a = A[m * 64 + lane];
    float p = t * a;
#pragma unroll
    for (int off = 32; off; off >>= 1) p += __shfl_xor(p, off, 64);
    atbv = fmaf(a, p, atbv);
  }

  unsigned int mprm = (unsigned int)(uintptr_t)(Mperm + lane * 64);
  unsigned int rb = (unsigned int)(uintptr_t)(&rbuf[wid][0]);
  unsigned int a_w = rb + lane * 4;
  unsigned int a_rf = rb + (((lane & 32) ^ 32) << 2);  // far 32-half base
  unsigned int a_nxt = ((lane + 1) & 63) * 4;          // bpermute lane+1
  float xin = x0[s * 64 + lane];
  float xout;
  int cnt_s;
  const int smask = 0x7fffffff;
  const float sthr = 5e-5f, sc02 = 0.2f, sc5 = 5.0f;

  asm volatile(
      "s_mov_b32 m0, -1\n\t"
      // --- M' row from LDS into v64-v127 ---
      "ds_read_b128 v[64:67],   %[mprm]\n\t"
      "ds_read_b128 v[68:71],   %[mprm] offset:16\n\t"
      "ds_read_b128 v[72:75],   %[mprm] offset:32\n\t"
      "ds_read_b128 v[76:79],   %[mprm] offset:48\n\t"
      "ds_read_b128 v[80:83],   %[mprm] offset:64\n\t"
      "ds_read_b128 v[84:87],   %[mprm] offset:80\n\t"
      "ds_read_b128 v[88:91],   %[mprm] offset:96\n\t"
      "ds_read_b128 v[92:95],   %[mprm] offset:112\n\t"
      "ds_read_b128 v[96:99],   %[mprm] offset:128\n\t"
      "ds_read_b128 v[100:103], %[mprm] offset:144\n\t"
      "ds_read_b128 v[104:107], %[mprm] offset:160\n\t"
      "ds_read_b128 v[108:111], %[mprm] offset:176\n\t"
      "ds_read_b128 v[112:115], %[mprm] offset:192\n\t"
      "ds_read_b128 v[116:119], %[mprm] offset:208\n\t"
      "ds_read_b128 v[120:123], %[mprm] offset:224\n\t"
      "ds_read_b128 v[124:127], %[mprm] offset:240\n\t"
      // --- init: v32=x v33=eta v34=tau v35=Dx v36=atb ---
      "v_mov_b32 v32, %[xin]\n\t"
      "v_mov_b32 v36, %[atb]\n\t"
      "v_mov_b32 v33, 0\n\t"
      "v_mov_b32 v34, 0\n\t"
      "ds_bpermute_b32 v45, %[anx], v32\n\t"
      "s_waitcnt lgkmcnt(0)\n\t"
      "v_sub_f32 v35, v45, v32\n\t"
      "s_movk_i32 %[cnt], 200\n\t"
      "1:\n\t"
      // u = copysign(max(|0.5*eta+Dx|-thr,0), .) -> v42
      "v_fma_f32 v40, 0.5, v33, v35\n\t"
      "v_and_b32 v41, %[msk], v40\n\t"
      "v_subrev_f32 v41, %[thr], v41\n\t"
      "v_max_f32 v41, 0, v41\n\t"
      "v_bfi_b32 v42, %[msk], v41, v40\n\t"
      // w = max(0.2*tau + x, 0) -> v43
      "v_fma_f32 v43, %[c02], v34, v32\n\t"
      "v_max_f32 v43, 0, v43\n\t"
      // tv = 2u - eta -> v40 ; ts = tv[lane+1] -> v45
      "v_fma_f32 v40, 2.0, v42, -v33\n\t"
      "ds_bpermute_b32 v45, %[anx], v40\n\t"
      // resid = 5w + atb - tau - tv + ts -> v44
      "v_fma_f32 v44, %[c5], v43, v36\n\t"
      "v_sub_f32 v44, v44, v34\n\t"
      "v_sub_f32 v44, v44, v40\n\t"
      "s_waitcnt lgkmcnt(0)\n\t"
      "v_add_f32 v44, v44, v45\n\t"
      // stage sources: write resid, xor16 swizzle, 8 far-half quad reads
      "ds_write_b32 %[aw], v44\n\t"
      "ds_swizzle_b32 v47, v44 offset:0x401F\n\t"
      "ds_read_b128 v[48:51], %[arf]\n\t"
      "ds_read_b128 v[52:55], %[arf] offset:16\n\t"
      "ds_read_b128 v[56:59], %[arf] offset:32\n\t"
      "ds_read_b128 v[60:63], %[arf] offset:48\n\t"
      "ds_read_b128 v[16:19], %[arf] offset:64\n\t"
      "ds_read_b128 v[20:23], %[arf] offset:80\n\t"
      "ds_read_b128 v[24:27], %[arf] offset:96\n\t"
      "ds_read_b128 v[28:31], %[arf] offset:112\n\t"
      // ---- stage 0: r=v44 (local), m=v64-79, DPP broadcasts ----
      "v_mul_f32 v37, v44, v64\n\t"
      DPL("v_mul_f32",  "v38", "v44", "v65", 1)
      DPL("v_mul_f32",  "v39", "v44", "v66", 2)
      DPL("v_mul_f32",  "v40", "v44", "v67", 3)
      DPL("v_fmac_f32", "v37", "v44", "v68", 4)
      DPL("v_fmac_f32", "v38", "v44", "v69", 5)
      DPL("v_fmac_f32", "v39", "v44", "v70", 6)
      DPL("v_fmac_f32", "v40", "v44", "v71", 7)
      DPL("v_fmac_f32", "v37", "v44", "v72", 8)
      DPL("v_fmac_f32", "v38", "v44", "v73", 9)
      DPL("v_fmac_f32", "v39", "v44", "v74", 10)
      DPL("v_fmac_f32", "v40", "v44", "v75", 11)
      DPL("v_fmac_f32", "v37", "v44", "v76", 12)
      DPL("v_fmac_f32", "v38", "v44", "v77", 13)
      DPL("v_fmac_f32", "v39", "v44", "v78", 14)
      DPL("v_fmac_f32", "v40", "v44", "v79", 15)
      // write+swizzle retired (10 outstanding -> 8): v47 ready
      "s_waitcnt lgkmcnt(8)\n\t"
      "s_nop 1\n\t"
      // ---- stage 1: r=v47 (xor16), m=v80-95 ----
      "v_fmac_f32 v37, v47, v80\n\t"
      DPL("v_fmac_f32", "v38", "v47", "v81", 1)
      DPL("v_fmac_f32", "v39", "v47", "v82", 2)
      DPL("v_fmac_f32", "v40", "v47", "v83", 3)
      DPL("v_fmac_f32", "v37", "v47", "v84", 4)
      DPL("v_fmac_f32", "v38", "v47", "v85", 5)
      DPL("v_fmac_f32", "v39", "v47", "v86", 6)
      DPL("v_fmac_f32", "v40", "v47", "v87", 7)
      DPL("v_fmac_f32", "v37", "v47", "v88", 8)
      DPL("v_fmac_f32", "v38", "v47", "v89", 9)
      DPL("v_fmac_f32", "v39", "v47", "v90", 10)
      DPL("v_fmac_f32", "v40", "v47", "v91", 11)
      DPL("v_fmac_f32", "v37", "v47", "v92", 12)
      DPL("v_fmac_f32", "v38", "v47", "v93", 13)
      DPL("v_fmac_f32", "v39", "v47", "v94", 14)
      DPL("v_fmac_f32", "v40", "v47", "v95", 15)
      // first 4 quads ready
      "s_waitcnt lgkmcnt(4)\n\t"
      // ---- stage 2: far[0..15] = v48-63, m=v96-111, plain 2-cyc fmacs ----
      "v_fmac_f32 v37, v48, v96\n\t"
      "v_fmac_f32 v38, v49, v97\n\t"
      "v_fmac_f32 v39, v50, v98\n\t"
      "v_fmac_f32 v40, v51, v99\n\t"
      "v_fmac_f32 v37, v52, v100\n\t"
      "v_fmac_f32 v38, v53, v101\n\t"
      "v_fmac_f32 v39, v54, v102\n\t"
      "v_fmac_f32 v40, v55, v103\n\t"
      "v_fmac_f32 v37, v56, v104\n\t"
      "v_fmac_f32 v38, v57, v105\n\t"
      "v_fmac_f32 v39, v58, v106\n\t"
      "v_fmac_f32 v40, v59, v107\n\t"
      "v_fmac_f32 v37, v60, v108\n\t"
      "v_fmac_f32 v38, v61, v109\n\t"
      "v_fmac_f32 v39, v62, v110\n\t"
      "v_fmac_f32 v40, v63, v111\n\t"
      "s_waitcnt lgkmcnt(0)\n\t"
      // ---- stage 3: far[16..31] = v16-31, m=v112-127 ----
      "v_fmac_f32 v37, v16, v112\n\t"
      "v_fmac_f32 v38, v17, v113\n\t"
      "v_fmac_f32 v39, v18, v114\n\t"
      "v_fmac_f32 v40, v19, v115\n\t"
      "v_fmac_f32 v37, v20, v116\n\t"
      "v_fmac_f32 v38, v21, v117\n\t"
      "v_fmac_f32 v39, v22, v118\n\t"
      "v_fmac_f32 v40, v23, v119\n\t"
      "v_fmac_f32 v37, v24, v120\n\t"
      "v_fmac_f32 v38, v25, v121\n\t"
      "v_fmac_f32 v39, v26, v122\n\t"
      "v_fmac_f32 v40, v27, v123\n\t"
      "v_fmac_f32 v37, v28, v124\n\t"
      "v_fmac_f32 v38, v29, v125\n\t"
      "v_fmac_f32 v39, v30, v126\n\t"
      "v_fmac_f32 v40, v31, v127\n\t"
      // combine -> x_new in v32
      "v_add_f32 v37, v37, v38\n\t"
      "v_add_f32 v39, v39, v40\n\t"
      "v_add_f32 v32, v37, v39\n\t"
      // Dx = x[lane+1] - x ; duals (tau update overlaps bpermute)
      "ds_bpermute_b32 v45, %[anx], v32\n\t"
      "v_sub_f32 v41, v32, v43\n\t"
      "v_fma_f32 v34, %[c5], v41, v34\n\t"
      "s_waitcnt lgkmcnt(0)\n\t"
      "v_sub_f32 v35, v45, v32\n\t"
      "v_sub_f32 v41, v35, v42\n\t"
      "v_fma_f32 v33, 2.0, v41, v33\n\t"
      "s_sub_u32 %[cnt], %[cnt], 1\n\t"
      "s_cmp_lg_u32 %[cnt], 0\n\t"
      "s_cbranch_scc1 1b\n\t"
      "v_mov_b32 %[xout], v32\n\t"
      : [xout] "=v"(xout), [cnt] "=&s"(cnt_s)
      : [mprm] "v"(mprm), [aw] "v"(a_w), [arf] "v"(a_rf), [anx] "v"(a_nxt),
        [xin] "v"(xin), [atb] "v"(atbv),
        [msk] "s"(smask), [thr] "s"(sthr), [c02] "s"(sc02), [c5] "s"(sc5)
      : "memory", "scc",
        "v16","v17","v18","v19","v20","v21","v22","v23","v24","v25","v26","v27",
        "v28","v29","v30","v31",
        "v32","v33","v34","v35","v36","v37","v38","v39","v40","v41","v42","v43",
        "v44","v45","v46","v47","v48","v49","v50","v51","v52","v53","v54","v55",
        "v56","v57","v58","v59","v60","v61","v62","v63","v64","v65","v66","v67",
        "v68","v69","v70","v71","v72","v73","v74","v75","v76","v77","v78","v79",
        "v80","v81","v82","v83","v84","v85","v86","v87","v88","v89","v90","v91",
        "v92","v93","v94","v95","v96","v97","v98","v99","v100","v101","v102",
        "v103","v104","v105","v106","v107","v108","v109","v110","v111","v112",
        "v113","v114","v115","v116","v117","v118","v119","v120","v121","v122",
        "v123","v124","v125","v126","v127");

  out[s * 64 + lane] = xout;
}

extern "C" void kernel_launch(void* const* d_in, const int* in_sizes, int n_in,
                              void* d_out, int out_size, void* d_ws, size_t ws_size,
                              hipStream_t stream) {
  const float* target = (const float*)d_in[0];  // (4096, 64)
  const float* A = (const float*)d_in[1];       // (9, 64)
  const float* x0 = (const float*)d_in[2];      // (4096, 64)
  float* out = (float*)d_out;                   // (4096, 64)

  admm_fused<<<NSAMP / 4, 256, 0, stream>>>(target, A, x0, out);
}